// Round 2
// baseline (1290.412 us; speedup 1.0000x reference)
//
#include <hip/hip_runtime.h>
#include <stdint.h>

// Problem: ComplexDepthwiseBatchNorm  N=16384, C=8, F=257
// Layout: x[N][C*F] row-major; NCOLS = 2056 columns per row.
// Dtype of x / W / out is detected ON DEVICE (bf16 vs fp32) — see detect_kernel.
#define NROWS   16384
#define NCOLS   2056
#define NG      257          // groups of 8 elements per row (2056/8)
#define EPSV    1e-6f
#define DELTA_MAX 1e8f
#define NSUM    (5*NCOLS)    // 10280 partial-sum slots (5 stats x 2056 cols)
#define LDSW    2124         // padded per-stat LDS stride: 2056 + 2056/32 + slack

__device__ __forceinline__ float bf_lo(uint32_t u) {
    return __builtin_bit_cast(float, u << 16);
}
__device__ __forceinline__ float bf_hi(uint32_t u) {
    return __builtin_bit_cast(float, u & 0xffff0000u);
}
__device__ __forceinline__ float bf1(uint16_t u) {
    return __builtin_bit_cast(float, (uint32_t)u << 16);
}
// round-to-nearest-even bf16 pair pack: lo -> bits[15:0], hi -> bits[31:16]
__device__ __forceinline__ uint32_t bf16pair(float lo, float hi) {
    uint32_t ul = __builtin_bit_cast(uint32_t, lo);
    uint32_t uh = __builtin_bit_cast(uint32_t, hi);
    ul = (ul + 0x7fffu + ((ul >> 16) & 1u)) >> 16;
    uh = (uh + 0x7fffu + ((uh >> 16) & 1u)) & 0xffff0000u;
    return ul | uh;
}

// ---------------- Pass 0: dtype detection ----------------
// flags[0]=1 iff x is fp32; flags[1]=1 iff W/B are fp32.
__global__ __launch_bounds__(512) void detect_kernel(
    const uint32_t* __restrict__ xr_u, const uint32_t* __restrict__ wrr_u,
    int* __restrict__ flags)
{
    __shared__ int cnt[2];
    if (threadIdx.x < 2) cnt[threadIdx.x] = 0;
    __syncthreads();
    const int part = threadIdx.x >> 8;                    // 0: x, 1: Wrr
    const uint32_t u = part ? wrr_u[threadIdx.x & 255] : xr_u[threadIdx.x & 255];
    const uint32_t e = (u >> 7) & 0xFFu;
    const int ok = (e >= 100u && e <= 131u) ? 1 : 0;
    atomicAdd(&cnt[part], ok);
    __syncthreads();
    if (threadIdx.x == 0) {
        flags[0] = (cnt[0] < 128) ? 1 : 0;
        flags[1] = (cnt[1] < 128) ? 1 : 0;
    }
}

// ---------------- Pass 1: per-column sums (flat stream + LDS atomics) -------
// Grid-stride over the FLAT float4/uint4 stream of xr & xi — identical address
// pattern to the harness fill that measures 6.4 TB/s. Column of element e is
// e % 2056; per-thread col advances by a constant step each iteration (passed
// from host), so no per-iter div/mod. Stats accumulate into a bank-swizzled
// LDS array (idx = col + (col>>5): lanes spaced 4 (fp32) or 8 (bf16) cols land
// 2-way per bank = free, vs 8/16-way unswizzled). Each block writes its 41 KB
// partial block to global (plain coalesced stores — no global-atomic
// write-through, no memset needed).
__global__ __launch_bounds__(1024) void stats_kernel(
    const void* __restrict__ xr_p, const void* __restrict__ xi_p,
    const int* __restrict__ flags, float* __restrict__ partials,
    int TT, int cstep_f32, int cstep_bf16)
{
    __shared__ float lds[5 * LDSW];
    for (int i = threadIdx.x; i < 5 * LDSW; i += 1024) lds[i] = 0.f;
    __syncthreads();

    const int tid = blockIdx.x * 1024 + threadIdx.x;

    if (flags[0]) {
        // -------- fp32: x is 16384*514 float4s, col(e)=e%2056, e=4*i --------
        const float4* __restrict__ xr4 = (const float4*)xr_p;
        const float4* __restrict__ xi4 = (const float4*)xi_p;
        const int T4 = NROWS * (NCOLS / 4);          // 8,421,376
        int c = (int)((4u * (uint32_t)tid) % (uint32_t)NCOLS);
        #pragma unroll 2
        for (int i = tid; i < T4; i += TT) {
            const float4 a = xr4[i];
            const float4 b = xi4[i];
            const float xr[4] = {a.x, a.y, a.z, a.w};
            const float xi[4] = {b.x, b.y, b.z, b.w};
            #pragma unroll
            for (int u = 0; u < 4; ++u) {
                const int cu = c + u;
                const int o  = cu + (cu >> 5);
                atomicAdd(&lds[0*LDSW + o], xr[u]);
                atomicAdd(&lds[1*LDSW + o], xi[u]);
                atomicAdd(&lds[2*LDSW + o], xr[u]*xr[u]);
                atomicAdd(&lds[3*LDSW + o], xr[u]*xi[u]);
                atomicAdd(&lds[4*LDSW + o], xi[u]*xi[u]);
            }
            c += cstep_f32; if (c >= NCOLS) c -= NCOLS;
        }
    } else {
        // -------- bf16: x is 16384*257 uint4s (8 bf16), col(e)=e%2056, e=8*i -
        const uint4* __restrict__ xr4 = (const uint4*)xr_p;
        const uint4* __restrict__ xi4 = (const uint4*)xi_p;
        const int T8 = NROWS * (NCOLS / 8);          // 4,210,688
        int c = (int)((8u * (uint32_t)tid) % (uint32_t)NCOLS);
        #pragma unroll 2
        for (int i = tid; i < T8; i += TT) {
            const uint4 a = xr4[i];
            const uint4 b = xi4[i];
            const uint32_t au[4] = {a.x, a.y, a.z, a.w};
            const uint32_t bu[4] = {b.x, b.y, b.z, b.w};
            #pragma unroll
            for (int j = 0; j < 4; ++j) {
                const float r0 = bf_lo(au[j]), r1 = bf_hi(au[j]);
                const float i0 = bf_lo(bu[j]), i1 = bf_hi(bu[j]);
                const int c0i = c + 2*j;
                const int c1i = c0i + 1;
                const int o0  = c0i + (c0i >> 5);
                const int o1  = c1i + (c1i >> 5);
                atomicAdd(&lds[0*LDSW + o0], r0);
                atomicAdd(&lds[1*LDSW + o0], i0);
                atomicAdd(&lds[2*LDSW + o0], r0*r0);
                atomicAdd(&lds[3*LDSW + o0], r0*i0);
                atomicAdd(&lds[4*LDSW + o0], i0*i0);
                atomicAdd(&lds[0*LDSW + o1], r1);
                atomicAdd(&lds[1*LDSW + o1], i1);
                atomicAdd(&lds[2*LDSW + o1], r1*r1);
                atomicAdd(&lds[3*LDSW + o1], r1*i1);
                atomicAdd(&lds[4*LDSW + o1], i1*i1);
            }
            c += cstep_bf16; if (c >= NCOLS) c -= NCOLS;
        }
    }

    __syncthreads();
    // write this block's partial sums: partials[bid][stat*2056 + col]
    float* __restrict__ dst = partials + (size_t)blockIdx.x * NSUM;
    for (int idx = threadIdx.x; idx < NSUM; idx += 1024) {
        const int s   = idx / NCOLS;
        const int col = idx - s * NCOLS;
        dst[idx] = lds[s * LDSW + col + (col >> 5)];
    }
}

// ---------------- Pass 1b: reduce partials over blocks ----------------
// block = 256 thr = 64 slots x 4 block-lanes; coalesced 64-wide reads.
__global__ __launch_bounds__(256) void reduce_kernel(
    const float* __restrict__ partials, float* __restrict__ sums, int NB)
{
    const int j  = blockIdx.x * 64 + (threadIdx.x & 63);
    const int bl = threadIdx.x >> 6;
    float s = 0.f;
    if (j < NSUM) {
        #pragma unroll 4
        for (int b = bl; b < NB; b += 4)
            s += partials[(size_t)b * NSUM + j];
    }
    __shared__ float red[256];
    red[threadIdx.x] = s;
    __syncthreads();
    if (threadIdx.x < 64 && j < NSUM)
        sums[j] = red[threadIdx.x] + red[threadIdx.x + 64] +
                  red[threadIdx.x + 128] + red[threadIdx.x + 192];
}

// ---------------- Pass 2: sums -> per-column coefficients ----------------
__global__ __launch_bounds__(256) void coef_kernel(
    const float* __restrict__ sums,
    const void* __restrict__ Wrr_p, const void* __restrict__ Wri_p,
    const void* __restrict__ Wii_p, const void* __restrict__ Br_p,
    const void* __restrict__ Bi_p,
    const int* __restrict__ flags, float* __restrict__ coef)
{
    const int j = blockIdx.x * 256 + threadIdx.x;
    if (j >= NCOLS) return;
    const float invN = 1.0f / (float)NROWS;
    const float Mr  = sums[0*NCOLS+j] * invN;
    const float Mi  = sums[1*NCOLS+j] * invN;
    const float Vrr = sums[2*NCOLS+j] * invN - Mr * Mr;
    const float Vri = sums[3*NCOLS+j] * invN - Mr * Mi;
    const float Vii = sums[4*NCOLS+j] * invN - Mi * Mi;
    const float tau   = Vrr + Vii;
    const float delta = fminf(fmaxf(Vrr * Vii - Vri * Vri, EPSV), DELTA_MAX);
    const float s   = sqrtf(delta);
    const float t   = sqrtf(tau + 2.0f * s);
    const float rst = 1.0f / (s * t);
    const float Urr = (s + Vii) * rst;
    const float Uii = (s + Vrr) * rst;
    const float Uri = -Vri * rst;

    float wrr, wri, wii, br, bi;
    if (flags[1]) {
        wrr = ((const float*)Wrr_p)[j];  wri = ((const float*)Wri_p)[j];
        wii = ((const float*)Wii_p)[j];
        br  = ((const float*)Br_p)[j];   bi  = ((const float*)Bi_p)[j];
    } else {
        wrr = bf1(((const uint16_t*)Wrr_p)[j]);  wri = bf1(((const uint16_t*)Wri_p)[j]);
        wii = bf1(((const uint16_t*)Wii_p)[j]);
        br  = bf1(((const uint16_t*)Br_p)[j]);   bi  = bf1(((const uint16_t*)Bi_p)[j]);
    }
    const float Zrr = wrr * Urr + wri * Uri;
    const float Zri = wrr * Uri + wri * Uii;
    const float Zir = wri * Urr + wii * Uri;
    const float Zii = wri * Uri + wii * Uii;
    coef[0*NCOLS+j] = Zrr;
    coef[1*NCOLS+j] = Zri;
    coef[2*NCOLS+j] = Zir;
    coef[3*NCOLS+j] = Zii;
    coef[4*NCOLS+j] = br - Zrr * Mr - Zri * Mi;
    coef[5*NCOLS+j] = bi - Zir * Mr - Zii * Mi;
}

// ---------------- Pass 3: apply (column-stationary, coeffs in regs) ----------
// grid 2056 x block 256 => T = 526336 = 2048*257 (bijection tid->(r0,c)).
// Flat-contiguous: consecutive tids touch consecutive 32 B chunks. Plain
// vector stores (NT stores reverted — round-0 plain stores were not the limit).
__global__ __launch_bounds__(256) void apply_kernel(
    const void* __restrict__ xr_p, const void* __restrict__ xi_p,
    const float* __restrict__ coef, const int* __restrict__ flags,
    void* __restrict__ out_p)
{
    const int tid = blockIdx.x * 256 + threadIdx.x;
    const int c  = tid % NG;
    const int r0 = tid / NG;            // [0,2048)
    const int col = c * 8;

    float Z[6][8];
    #pragma unroll
    for (int t = 0; t < 6; ++t) {
        const float4 lo = *(const float4*)(coef + t*NCOLS + col);
        const float4 hi = *(const float4*)(coef + t*NCOLS + col + 4);
        Z[t][0]=lo.x; Z[t][1]=lo.y; Z[t][2]=lo.z; Z[t][3]=lo.w;
        Z[t][4]=hi.x; Z[t][5]=hi.y; Z[t][6]=hi.z; Z[t][7]=hi.w;
    }

    if (flags[0]) {
        // -------- fp32 path --------
        const float4* xr4 = (const float4*)xr_p;
        const float4* xi4 = (const float4*)xi_p;
        float4* yr4 = (float4*)out_p;
        float4* yi4 = yr4 + (size_t)NROWS * 514;   // yi after N*C*F floats
        #pragma unroll 2
        for (int k = 0; k < 8; ++k) {
            const size_t g = (size_t)(r0 + (k << 11)) * 514 + 2 * c;
            const float4 a0 = xr4[g], a1 = xr4[g + 1];
            const float4 b0 = xi4[g], b1 = xi4[g + 1];
            const float xrv[8] = {a0.x,a0.y,a0.z,a0.w,a1.x,a1.y,a1.z,a1.w};
            const float xiv[8] = {b0.x,b0.y,b0.z,b0.w,b1.x,b1.y,b1.z,b1.w};
            float yrv[8], yiv[8];
            #pragma unroll
            for (int j = 0; j < 8; ++j) {
                yrv[j] = Z[0][j]*xrv[j] + Z[1][j]*xiv[j] + Z[4][j];
                yiv[j] = Z[2][j]*xrv[j] + Z[3][j]*xiv[j] + Z[5][j];
            }
            yr4[g]     = make_float4(yrv[0], yrv[1], yrv[2], yrv[3]);
            yr4[g + 1] = make_float4(yrv[4], yrv[5], yrv[6], yrv[7]);
            yi4[g]     = make_float4(yiv[0], yiv[1], yiv[2], yiv[3]);
            yi4[g + 1] = make_float4(yiv[4], yiv[5], yiv[6], yiv[7]);
        }
    } else {
        // -------- bf16 path --------
        const uint4* xr4 = (const uint4*)xr_p;
        const uint4* xi4 = (const uint4*)xi_p;
        uint4* yr4 = (uint4*)out_p;
        uint4* yi4 = yr4 + (size_t)NROWS * NG;     // yi after N*C*F bf16
        #pragma unroll 2
        for (int k = 0; k < 8; ++k) {
            const size_t g = (size_t)(r0 + (k << 11)) * NG + c;
            const uint4 a = xr4[g];
            const uint4 b = xi4[g];
            const uint32_t au[4] = {a.x, a.y, a.z, a.w};
            const uint32_t bu[4] = {b.x, b.y, b.z, b.w};
            uint32_t ou[4], pu[4];
            #pragma unroll
            for (int j = 0; j < 4; ++j) {
                const int e0 = 2*j, e1 = 2*j + 1;
                const float xr0 = bf_lo(au[j]), xr1 = bf_hi(au[j]);
                const float xi0 = bf_lo(bu[j]), xi1 = bf_hi(bu[j]);
                const float yr0 = Z[0][e0]*xr0 + Z[1][e0]*xi0 + Z[4][e0];
                const float yi0 = Z[2][e0]*xr0 + Z[3][e0]*xi0 + Z[5][e0];
                const float yr1 = Z[0][e1]*xr1 + Z[1][e1]*xi1 + Z[4][e1];
                const float yi1 = Z[2][e1]*xr1 + Z[3][e1]*xi1 + Z[5][e1];
                ou[j] = bf16pair(yr0, yr1);
                pu[j] = bf16pair(yi0, yi1);
            }
            yr4[g] = make_uint4(ou[0], ou[1], ou[2], ou[3]);
            yi4[g] = make_uint4(pu[0], pu[1], pu[2], pu[3]);
        }
    }
}

extern "C" void kernel_launch(void* const* d_in, const int* in_sizes, int n_in,
                              void* d_out, int out_size, void* d_ws, size_t ws_size,
                              hipStream_t stream)
{
    const void* xr_p = d_in[0];
    const void* xi_p = d_in[1];
    const void* Wrr  = d_in[2];
    const void* Wri  = d_in[3];
    const void* Wii  = d_in[4];
    const void* Br   = d_in[5];
    const void* Bi   = d_in[6];

    float* sums  = (float*)d_ws;                 // 5 * 2056 f32
    float* coef  = sums + NSUM;                  // 6 * 2056 f32
    int*   flags = (int*)(coef + 6 * NCOLS);     // 2 ints (pad to 4)
    float* partials = (float*)(flags + 4);       // NB * NSUM f32

    // pick NB (stats blocks) by available workspace; 512 => 2 blocks/CU (100% occ)
    const size_t base_bytes = (size_t)(NSUM + 6 * NCOLS + 4) * 4;
    int NB = 512;
    while (NB > 64 && base_bytes + (size_t)NB * NSUM * 4 > ws_size) NB >>= 1;
    const int TT = NB * 1024;
    const int cstep_f32  = (int)(((unsigned long long)4 * TT) % NCOLS);
    const int cstep_bf16 = (int)(((unsigned long long)8 * TT) % NCOLS);

    detect_kernel<<<1, 512, 0, stream>>>((const uint32_t*)xr_p, (const uint32_t*)Wrr, flags);
    stats_kernel<<<NB, 1024, 0, stream>>>(xr_p, xi_p, flags, partials, TT, cstep_f32, cstep_bf16);
    reduce_kernel<<<(NSUM + 63) / 64, 256, 0, stream>>>(partials, sums, NB);
    coef_kernel<<<(NCOLS + 255) / 256, 256, 0, stream>>>(sums, Wrr, Wri, Wii, Br, Bi, flags, coef);
    apply_kernel<<<2056, 256, 0, stream>>>(xr_p, xi_p, coef, flags, d_out);
}

// Round 3
// 549.965 us; speedup vs baseline: 2.3464x; 2.3464x over previous
//
#include <hip/hip_runtime.h>
#include <stdint.h>

// Problem: ComplexDepthwiseBatchNorm  N=16384, C=8, F=257
// Layout: x[N][C*F] row-major; NCOLS = 2056 columns per row.
// Dtype of x / W / out is detected ON DEVICE (bf16 vs fp32) — see detect_kernel.
#define NROWS   16384
#define NCOLS   2056
#define NG      257          // groups of 8 elements per row (2056/8)
#define EPSV    1e-6f
#define DELTA_MAX 1e8f
#define SR      64           // row slices for stats (NROWS/SR = 256 rows/slice)

__device__ __forceinline__ float bf_lo(uint32_t u) {
    return __builtin_bit_cast(float, u << 16);
}
__device__ __forceinline__ float bf_hi(uint32_t u) {
    return __builtin_bit_cast(float, u & 0xffff0000u);
}
__device__ __forceinline__ float bf1(uint16_t u) {
    return __builtin_bit_cast(float, (uint32_t)u << 16);
}
// round-to-nearest-even bf16 pair pack: lo -> bits[15:0], hi -> bits[31:16]
__device__ __forceinline__ uint32_t bf16pair(float lo, float hi) {
    uint32_t ul = __builtin_bit_cast(uint32_t, lo);
    uint32_t uh = __builtin_bit_cast(uint32_t, hi);
    ul = (ul + 0x7fffu + ((ul >> 16) & 1u)) >> 16;
    uh = (uh + 0x7fffu + ((uh >> 16) & 1u)) & 0xffff0000u;
    return ul | uh;
}

// ---------------- Pass 0: dtype detection ----------------
// flags[0]=1 iff x is fp32; flags[1]=1 iff W/B are fp32.
__global__ __launch_bounds__(512) void detect_kernel(
    const uint32_t* __restrict__ xr_u, const uint32_t* __restrict__ wrr_u,
    int* __restrict__ flags)
{
    __shared__ int cnt[2];
    if (threadIdx.x < 2) cnt[threadIdx.x] = 0;
    __syncthreads();
    const int part = threadIdx.x >> 8;                    // 0: x, 1: Wrr
    const uint32_t u = part ? wrr_u[threadIdx.x & 255] : xr_u[threadIdx.x & 255];
    const uint32_t e = (u >> 7) & 0xFFu;
    const int ok = (e >= 100u && e <= 131u) ? 1 : 0;
    atomicAdd(&cnt[part], ok);
    __syncthreads();
    if (threadIdx.x == 0) {
        flags[0] = (cnt[0] < 128) ? 1 : 0;
        flags[1] = (cnt[1] < 128) ? 1 : 0;
    }
}

// ---------------- stat accumulation helpers ----------------
// acc layout: acc[stat*8 + colj], stats: 0=sr 1=si 2=srr 3=sri 4=sii
__device__ __forceinline__ void accum_bf16x8(float* acc, uint4 a, uint4 b) {
    const uint32_t au[4] = {a.x, a.y, a.z, a.w};
    const uint32_t bu[4] = {b.x, b.y, b.z, b.w};
    #pragma unroll
    for (int j = 0; j < 4; ++j) {
        const float r0 = bf_lo(au[j]), r1 = bf_hi(au[j]);
        const float i0 = bf_lo(bu[j]), i1 = bf_hi(bu[j]);
        acc[0*8 + 2*j]     += r0;       acc[1*8 + 2*j]     += i0;
        acc[2*8 + 2*j]     += r0*r0;    acc[3*8 + 2*j]     += r0*i0;
        acc[4*8 + 2*j]     += i0*i0;
        acc[0*8 + 2*j + 1] += r1;       acc[1*8 + 2*j + 1] += i1;
        acc[2*8 + 2*j + 1] += r1*r1;    acc[3*8 + 2*j + 1] += r1*i1;
        acc[4*8 + 2*j + 1] += i1*i1;
    }
}
__device__ __forceinline__ void accum_f32x8(float* acc, float4 a0, float4 a1,
                                            float4 b0, float4 b1) {
    const float xr[8] = {a0.x,a0.y,a0.z,a0.w,a1.x,a1.y,a1.z,a1.w};
    const float xi[8] = {b0.x,b0.y,b0.z,b0.w,b1.x,b1.y,b1.z,b1.w};
    #pragma unroll
    for (int j = 0; j < 8; ++j) {
        acc[0*8 + j] += xr[j];        acc[1*8 + j] += xi[j];
        acc[2*8 + j] += xr[j]*xr[j];  acc[3*8 + j] += xr[j]*xi[j];
        acc[4*8 + j] += xi[j]*xi[j];
    }
}

// ---------------- Pass 1: per-column sums (tile-stationary) ----------------
// grid dim3(SR, 33) x block 256  (round-1 structure, register accumulators).
//   blockIdx.x = rs (row slice, 256 rows), blockIdx.y = ct (column tile).
//   ct < 32 : block owns column groups [8ct, 8ct+8). thread t: group = 8ct+(t&7),
//             row-lane = t>>3 (32 lanes/group), 8 rows each.
//             Lanes 0-7 read 128 B contiguous -> full-line requests.
//   ct == 32: leftover group 256; thread t owns row rbase+t (1 load).
// Reduction: shfl_xor over row-lanes -> LDS combine over 4 waves ->
//            320 global atomics/block (native f32 atomic: 21 MB write-through).
__global__ __launch_bounds__(256) void stats_kernel(
    const void* __restrict__ xr_p, const void* __restrict__ xi_p,
    const int* __restrict__ flags, float* __restrict__ sums)
{
    const int rs = blockIdx.x;          // 0..SR-1
    const int ct = blockIdx.y;          // 0..32
    const int t  = threadIdx.x;
    const int rbase = rs * (NROWS / SR);   // 256 rows per slice

    float acc[40];
    #pragma unroll
    for (int j = 0; j < 40; ++j) acc[j] = 0.f;

    const bool isfp32 = (flags[0] != 0);

    if (ct < 32) {
        const int grp = ct * 8 + (t & 7);
        const int rl  = t >> 3;             // 0..31
        if (!isfp32) {
            const uint4* xr4 = (const uint4*)xr_p;
            const uint4* xi4 = (const uint4*)xi_p;
            #pragma unroll 2
            for (int k = 0; k < 8; ++k) {
                const size_t g = (size_t)(rbase + rl + 32*k) * NG + grp;
                accum_bf16x8(acc, xr4[g], xi4[g]);
            }
        } else {
            const float4* xr4 = (const float4*)xr_p;
            const float4* xi4 = (const float4*)xi_p;
            #pragma unroll 2
            for (int k = 0; k < 8; ++k) {
                const size_t g = (size_t)(rbase + rl + 32*k) * 514 + 2*grp;
                accum_f32x8(acc, xr4[g], xr4[g+1], xi4[g], xi4[g+1]);
            }
        }
        // reduce over the 8 row-lanes sharing this group (lane bits 3..5)
        #pragma unroll
        for (int j = 0; j < 40; ++j) acc[j] += __shfl_xor(acc[j], 8, 64);
        #pragma unroll
        for (int j = 0; j < 40; ++j) acc[j] += __shfl_xor(acc[j], 16, 64);
        #pragma unroll
        for (int j = 0; j < 40; ++j) acc[j] += __shfl_xor(acc[j], 32, 64);
    } else {
        // leftover group 256 (columns 2048..2055): one row per thread
        if (!isfp32) {
            const uint4* xr4 = (const uint4*)xr_p;
            const uint4* xi4 = (const uint4*)xi_p;
            const size_t g = (size_t)(rbase + t) * NG + 256;
            accum_bf16x8(acc, xr4[g], xi4[g]);
        } else {
            const float4* xr4 = (const float4*)xr_p;
            const float4* xi4 = (const float4*)xi_p;
            const size_t g = (size_t)(rbase + t) * 514 + 512;
            accum_f32x8(acc, xr4[g], xr4[g+1], xi4[g], xi4[g+1]);
        }
        // full 64-lane reduction
        #pragma unroll
        for (int m = 1; m <= 32; m <<= 1) {
            #pragma unroll
            for (int j = 0; j < 40; ++j) acc[j] += __shfl_xor(acc[j], m, 64);
        }
    }

    // cross-wave combine: per-wave representatives -> LDS -> sum 4 -> atomic
    __shared__ float red[4][320];
    const int wv = t >> 6, ln = t & 63;
    if (ct < 32) {
        if (ln < 8) {
            #pragma unroll
            for (int j = 0; j < 40; ++j) red[wv][ln*40 + j] = acc[j];
        }
    } else {
        if (ln == 0) {
            #pragma unroll
            for (int j = 0; j < 40; ++j) red[wv][j] = acc[j];
        }
    }
    __syncthreads();
    const int nvals = (ct < 32) ? 320 : 40;
    for (int idx = t; idx < nvals; idx += 256) {
        const float v = red[0][idx] + red[1][idx] + red[2][idx] + red[3][idx];
        const int gi  = idx / 40;
        const int j   = idx - gi * 40;          // stat*8 + colj
        const int col = (ct * 8 + gi) * 8 + (j & 7);
        atomicAdd(&sums[(j >> 3) * NCOLS + col], v);
    }
}

// ---------------- Pass 2: sums -> per-column coefficients ----------------
__global__ __launch_bounds__(256) void coef_kernel(
    const float* __restrict__ sums,
    const void* __restrict__ Wrr_p, const void* __restrict__ Wri_p,
    const void* __restrict__ Wii_p, const void* __restrict__ Br_p,
    const void* __restrict__ Bi_p,
    const int* __restrict__ flags, float* __restrict__ coef)
{
    const int j = blockIdx.x * 256 + threadIdx.x;
    if (j >= NCOLS) return;
    const float invN = 1.0f / (float)NROWS;
    const float Mr  = sums[0*NCOLS+j] * invN;
    const float Mi  = sums[1*NCOLS+j] * invN;
    const float Vrr = sums[2*NCOLS+j] * invN - Mr * Mr;
    const float Vri = sums[3*NCOLS+j] * invN - Mr * Mi;
    const float Vii = sums[4*NCOLS+j] * invN - Mi * Mi;
    const float tau   = Vrr + Vii;
    const float delta = fminf(fmaxf(Vrr * Vii - Vri * Vri, EPSV), DELTA_MAX);
    const float s   = sqrtf(delta);
    const float t   = sqrtf(tau + 2.0f * s);
    const float rst = 1.0f / (s * t);
    const float Urr = (s + Vii) * rst;
    const float Uii = (s + Vrr) * rst;
    const float Uri = -Vri * rst;

    float wrr, wri, wii, br, bi;
    if (flags[1]) {
        wrr = ((const float*)Wrr_p)[j];  wri = ((const float*)Wri_p)[j];
        wii = ((const float*)Wii_p)[j];
        br  = ((const float*)Br_p)[j];   bi  = ((const float*)Bi_p)[j];
    } else {
        wrr = bf1(((const uint16_t*)Wrr_p)[j]);  wri = bf1(((const uint16_t*)Wri_p)[j]);
        wii = bf1(((const uint16_t*)Wii_p)[j]);
        br  = bf1(((const uint16_t*)Br_p)[j]);   bi  = bf1(((const uint16_t*)Bi_p)[j]);
    }
    const float Zrr = wrr * Urr + wri * Uri;
    const float Zri = wrr * Uri + wri * Uii;
    const float Zir = wri * Urr + wii * Uri;
    const float Zii = wri * Uri + wii * Uii;
    coef[0*NCOLS+j] = Zrr;
    coef[1*NCOLS+j] = Zri;
    coef[2*NCOLS+j] = Zir;
    coef[3*NCOLS+j] = Zii;
    coef[4*NCOLS+j] = br - Zrr * Mr - Zri * Mi;
    coef[5*NCOLS+j] = bi - Zir * Mr - Zii * Mi;
}

// ---------------- Pass 3: apply (column-stationary, coeffs in regs) ----------
// grid 2056 x block 256 => T = 526336 = 2048*257 (bijection tid->(r0,c)).
// Flat-contiguous: consecutive tids touch consecutive 32 B chunks. Plain
// vector stores (NT/L2-bypass stores are the round-1 regression suspect).
__global__ __launch_bounds__(256) void apply_kernel(
    const void* __restrict__ xr_p, const void* __restrict__ xi_p,
    const float* __restrict__ coef, const int* __restrict__ flags,
    void* __restrict__ out_p)
{
    const int tid = blockIdx.x * 256 + threadIdx.x;
    const int c  = tid % NG;
    const int r0 = tid / NG;            // [0,2048)
    const int col = c * 8;

    float Z[6][8];
    #pragma unroll
    for (int t = 0; t < 6; ++t) {
        const float4 lo = *(const float4*)(coef + t*NCOLS + col);
        const float4 hi = *(const float4*)(coef + t*NCOLS + col + 4);
        Z[t][0]=lo.x; Z[t][1]=lo.y; Z[t][2]=lo.z; Z[t][3]=lo.w;
        Z[t][4]=hi.x; Z[t][5]=hi.y; Z[t][6]=hi.z; Z[t][7]=hi.w;
    }

    if (flags[0]) {
        // -------- fp32 path --------
        const float4* xr4 = (const float4*)xr_p;
        const float4* xi4 = (const float4*)xi_p;
        float4* yr4 = (float4*)out_p;
        float4* yi4 = yr4 + (size_t)NROWS * 514;   // yi after N*C*F floats
        #pragma unroll 2
        for (int k = 0; k < 8; ++k) {
            const size_t g = (size_t)(r0 + (k << 11)) * 514 + 2 * c;
            const float4 a0 = xr4[g], a1 = xr4[g + 1];
            const float4 b0 = xi4[g], b1 = xi4[g + 1];
            const float xrv[8] = {a0.x,a0.y,a0.z,a0.w,a1.x,a1.y,a1.z,a1.w};
            const float xiv[8] = {b0.x,b0.y,b0.z,b0.w,b1.x,b1.y,b1.z,b1.w};
            float yrv[8], yiv[8];
            #pragma unroll
            for (int j = 0; j < 8; ++j) {
                yrv[j] = Z[0][j]*xrv[j] + Z[1][j]*xiv[j] + Z[4][j];
                yiv[j] = Z[2][j]*xrv[j] + Z[3][j]*xiv[j] + Z[5][j];
            }
            yr4[g]     = make_float4(yrv[0], yrv[1], yrv[2], yrv[3]);
            yr4[g + 1] = make_float4(yrv[4], yrv[5], yrv[6], yrv[7]);
            yi4[g]     = make_float4(yiv[0], yiv[1], yiv[2], yiv[3]);
            yi4[g + 1] = make_float4(yiv[4], yiv[5], yiv[6], yiv[7]);
        }
    } else {
        // -------- bf16 path --------
        const uint4* xr4 = (const uint4*)xr_p;
        const uint4* xi4 = (const uint4*)xi_p;
        uint4* yr4 = (uint4*)out_p;
        uint4* yi4 = yr4 + (size_t)NROWS * NG;     // yi after N*C*F bf16
        #pragma unroll 2
        for (int k = 0; k < 8; ++k) {
            const size_t g = (size_t)(r0 + (k << 11)) * NG + c;
            const uint4 a = xr4[g];
            const uint4 b = xi4[g];
            const uint32_t au[4] = {a.x, a.y, a.z, a.w};
            const uint32_t bu[4] = {b.x, b.y, b.z, b.w};
            uint32_t ou[4], pu[4];
            #pragma unroll
            for (int j = 0; j < 4; ++j) {
                const int e0 = 2*j, e1 = 2*j + 1;
                const float xr0 = bf_lo(au[j]), xr1 = bf_hi(au[j]);
                const float xi0 = bf_lo(bu[j]), xi1 = bf_hi(bu[j]);
                const float yr0 = Z[0][e0]*xr0 + Z[1][e0]*xi0 + Z[4][e0];
                const float yi0 = Z[2][e0]*xr0 + Z[3][e0]*xi0 + Z[5][e0];
                const float yr1 = Z[0][e1]*xr1 + Z[1][e1]*xi1 + Z[4][e1];
                const float yi1 = Z[2][e1]*xr1 + Z[3][e1]*xi1 + Z[5][e1];
                ou[j] = bf16pair(yr0, yr1);
                pu[j] = bf16pair(yi0, yi1);
            }
            yr4[g] = make_uint4(ou[0], ou[1], ou[2], ou[3]);
            yi4[g] = make_uint4(pu[0], pu[1], pu[2], pu[3]);
        }
    }
}

extern "C" void kernel_launch(void* const* d_in, const int* in_sizes, int n_in,
                              void* d_out, int out_size, void* d_ws, size_t ws_size,
                              hipStream_t stream)
{
    const void* xr_p = d_in[0];
    const void* xi_p = d_in[1];
    const void* Wrr  = d_in[2];
    const void* Wri  = d_in[3];
    const void* Wii  = d_in[4];
    const void* Br   = d_in[5];
    const void* Bi   = d_in[6];

    float* sums  = (float*)d_ws;             // 5 * 2056 f32
    float* coef  = sums + 5 * NCOLS;         // 6 * 2056 f32
    int*   flags = (int*)(coef + 6 * NCOLS); // 2 ints

    detect_kernel<<<1, 512, 0, stream>>>((const uint32_t*)xr_p, (const uint32_t*)Wrr, flags);
    hipMemsetAsync(sums, 0, 5 * NCOLS * sizeof(float), stream);
    stats_kernel<<<dim3(SR, 33), 256, 0, stream>>>(xr_p, xi_p, flags, sums);
    coef_kernel<<<(NCOLS + 255) / 256, 256, 0, stream>>>(sums, Wrr, Wri, Wii, Br, Bi, flags, coef);
    apply_kernel<<<2056, 256, 0, stream>>>(xr_p, xi_p, coef, flags, d_out);
}

// Round 4
// 547.126 us; speedup vs baseline: 2.3585x; 1.0052x over previous
//
#include <hip/hip_runtime.h>
#include <stdint.h>

// Problem: ComplexDepthwiseBatchNorm  N=16384, C=8, F=257
// Layout: x[N][C*F] row-major; NCOLS = 2056 columns per row.
// Dtype of x / W / out is detected ON DEVICE (bf16 vs fp32) — see detect_kernel.
#define NROWS   16384
#define NCOLS   2056
#define NG      257            // groups of 8 bf16 (one uint4) per row
#define NQ      514            // groups of 4 fp32 (one float4) per row
#define EPSV    1e-6f
#define DELTA_MAX 1e8f
#define NSUM    (5*NCOLS)      // 10280 sum slots (5 stats x 2056 cols)
#define T8TOT   (NROWS*NG)     // 4,210,688 uint4 per bf16 tensor
#define T4TOT   (NROWS*NQ)     // 8,421,376 float4 per fp32 tensor

typedef float    f32x4 __attribute__((ext_vector_type(4)));
typedef uint32_t u32x4 __attribute__((ext_vector_type(4)));

__device__ __forceinline__ float bf_lo(uint32_t u) {
    return __builtin_bit_cast(float, u << 16);
}
__device__ __forceinline__ float bf_hi(uint32_t u) {
    return __builtin_bit_cast(float, u & 0xffff0000u);
}
__device__ __forceinline__ float bf1(uint16_t u) {
    return __builtin_bit_cast(float, (uint32_t)u << 16);
}
// round-to-nearest-even bf16 pair pack: lo -> bits[15:0], hi -> bits[31:16]
__device__ __forceinline__ uint32_t bf16pair(float lo, float hi) {
    uint32_t ul = __builtin_bit_cast(uint32_t, lo);
    uint32_t uh = __builtin_bit_cast(uint32_t, hi);
    ul = (ul + 0x7fffu + ((ul >> 16) & 1u)) >> 16;
    uh = (uh + 0x7fffu + ((uh >> 16) & 1u)) & 0xffff0000u;
    return ul | uh;
}

// ---------------- Pass 0: dtype detection ----------------
// flags[0]=1 iff x is fp32; flags[1]=1 iff W/B are fp32.
__global__ __launch_bounds__(512) void detect_kernel(
    const uint32_t* __restrict__ xr_u, const uint32_t* __restrict__ wrr_u,
    int* __restrict__ flags)
{
    __shared__ int cnt[2];
    if (threadIdx.x < 2) cnt[threadIdx.x] = 0;
    __syncthreads();
    const int part = threadIdx.x >> 8;                    // 0: x, 1: Wrr
    const uint32_t u = part ? wrr_u[threadIdx.x & 255] : xr_u[threadIdx.x & 255];
    const uint32_t e = (u >> 7) & 0xFFu;
    const int ok = (e >= 100u && e <= 131u) ? 1 : 0;
    atomicAdd(&cnt[part], ok);
    __syncthreads();
    if (threadIdx.x == 0) {
        flags[0] = (cnt[0] < 128) ? 1 : 0;
        flags[1] = (cnt[1] < 128) ? 1 : 0;
    }
}

// ---------------- Pass 1: per-column sums (FLAT stream, reg-stationary) -----
// grid NB x block 1024, TT = NB*1024 with NB in {514, 257}.
// Thread tid reads vector index  g = tid + k*TT  — perfectly contiguous per
// wave (identical address pattern to the 6.4 TB/s harness fill; no stride
// resonance with the HBM channel interleave, unlike the 4112 B row-stride
// tiled version that measured ~1 TB/s).
// Key invariant: TT ≡ 0 (mod 257) [bf16 u4-groups] AND ≡ 0 (mod 514) [fp32
// f4-groups], so each thread's column set (tid mod 257 / tid mod 514) is FIXED
// across iterations -> pure register accumulators, no atomics in the loop.
// Block combine: 4 (bf16) / 2 (fp32) serialized LDS += phases (threads with
// equal column index are exactly {t, t+257, ...} within the block), then one
// NT-stored 41 KB partial block per workgroup; reduce_kernel sums them.
__global__ __launch_bounds__(1024, 8) void stats_kernel(
    const void* __restrict__ xr_p, const void* __restrict__ xi_p,
    const int* __restrict__ flags, float* __restrict__ partials,
    int TT, int nit8, int nit4)
{
    __shared__ float lds[NSUM];
    const int t = threadIdx.x;
    for (int i = t; i < NSUM; i += 1024) lds[i] = 0.f;
    const int tid = blockIdx.x * 1024 + t;

    if (!flags[0]) {
        // -------- bf16: 8 fixed columns, 40 accumulators --------
        float acc[40];
        #pragma unroll
        for (int j = 0; j < 40; ++j) acc[j] = 0.f;
        const uint4* __restrict__ xr4 = (const uint4*)xr_p;
        const uint4* __restrict__ xi4 = (const uint4*)xi_p;
        for (int k = 0; k < nit8; ++k) {
            const size_t g = (size_t)tid + (size_t)k * TT;
            const uint4 a = xr4[g];
            const uint4 b = xi4[g];
            const uint32_t au[4] = {a.x, a.y, a.z, a.w};
            const uint32_t bu[4] = {b.x, b.y, b.z, b.w};
            #pragma unroll
            for (int j = 0; j < 4; ++j) {
                const float r0 = bf_lo(au[j]), r1 = bf_hi(au[j]);
                const float i0 = bf_lo(bu[j]), i1 = bf_hi(bu[j]);
                acc[0*8 + 2*j]     += r0;       acc[1*8 + 2*j]     += i0;
                acc[2*8 + 2*j]     += r0*r0;    acc[3*8 + 2*j]     += r0*i0;
                acc[4*8 + 2*j]     += i0*i0;
                acc[0*8 + 2*j + 1] += r1;       acc[1*8 + 2*j + 1] += i1;
                acc[2*8 + 2*j + 1] += r1*r1;    acc[3*8 + 2*j + 1] += r1*i1;
                acc[4*8 + 2*j + 1] += i1*i1;
            }
        }
        __syncthreads();                       // LDS zeroed + all loads done
        const int c  = tid % NG;               // fixed u4-group of this thread
        const int ph = t / NG;                 // 0..3 (block phase)
        for (int p = 0; p < 4; ++p) {
            if (ph == p) {
                #pragma unroll
                for (int s = 0; s < 5; ++s)
                    #pragma unroll
                    for (int j = 0; j < 8; ++j)
                        lds[s*NCOLS + c*8 + j] += acc[s*8 + j];
            }
            __syncthreads();
        }
    } else {
        // -------- fp32: 4 fixed columns, 20 accumulators --------
        float acc[20];
        #pragma unroll
        for (int j = 0; j < 20; ++j) acc[j] = 0.f;
        const float4* __restrict__ xr4 = (const float4*)xr_p;
        const float4* __restrict__ xi4 = (const float4*)xi_p;
        for (int k = 0; k < nit4; ++k) {
            const size_t g = (size_t)tid + (size_t)k * TT;
            const float4 a = xr4[g];
            const float4 b = xi4[g];
            const float xr[4] = {a.x, a.y, a.z, a.w};
            const float xi[4] = {b.x, b.y, b.z, b.w};
            #pragma unroll
            for (int j = 0; j < 4; ++j) {
                acc[0*4 + j] += xr[j];        acc[1*4 + j] += xi[j];
                acc[2*4 + j] += xr[j]*xr[j];  acc[3*4 + j] += xr[j]*xi[j];
                acc[4*4 + j] += xi[j]*xi[j];
            }
        }
        __syncthreads();
        const int cq = tid % NQ;               // fixed f4-group of this thread
        const int ph = t / NQ;                 // 0..1
        for (int p = 0; p < 2; ++p) {
            if (ph == p) {
                #pragma unroll
                for (int s = 0; s < 5; ++s)
                    #pragma unroll
                    for (int j = 0; j < 4; ++j)
                        lds[s*NCOLS + cq*4 + j] += acc[s*4 + j];
            }
            __syncthreads();
        }
    }

    // NT-store this block's partials (read once by reduce; keep x in L3)
    float* __restrict__ dst = partials + (size_t)blockIdx.x * NSUM;
    for (int i = t; i < NSUM; i += 1024)
        __builtin_nontemporal_store(lds[i], dst + i);
}

// ---------------- Pass 1b: reduce partials over blocks ----------------
// block = 256 thr = 64 slots x 4 block-lanes; coalesced 64-wide reads.
__global__ __launch_bounds__(256) void reduce_kernel(
    const float* __restrict__ partials, float* __restrict__ sums, int NB)
{
    const int j  = blockIdx.x * 64 + (threadIdx.x & 63);
    const int bl = threadIdx.x >> 6;
    float s = 0.f;
    if (j < NSUM) {
        #pragma unroll 4
        for (int b = bl; b < NB; b += 4)
            s += partials[(size_t)b * NSUM + j];
    }
    __shared__ float red[256];
    red[threadIdx.x] = s;
    __syncthreads();
    if (threadIdx.x < 64 && j < NSUM)
        sums[j] = red[threadIdx.x] + red[threadIdx.x + 64] +
                  red[threadIdx.x + 128] + red[threadIdx.x + 192];
}

// ---------------- Pass 2: sums -> per-column coefficients ----------------
__global__ __launch_bounds__(256) void coef_kernel(
    const float* __restrict__ sums,
    const void* __restrict__ Wrr_p, const void* __restrict__ Wri_p,
    const void* __restrict__ Wii_p, const void* __restrict__ Br_p,
    const void* __restrict__ Bi_p,
    const int* __restrict__ flags, float* __restrict__ coef)
{
    const int j = blockIdx.x * 256 + threadIdx.x;
    if (j >= NCOLS) return;
    const float invN = 1.0f / (float)NROWS;
    const float Mr  = sums[0*NCOLS+j] * invN;
    const float Mi  = sums[1*NCOLS+j] * invN;
    const float Vrr = sums[2*NCOLS+j] * invN - Mr * Mr;
    const float Vri = sums[3*NCOLS+j] * invN - Mr * Mi;
    const float Vii = sums[4*NCOLS+j] * invN - Mi * Mi;
    const float tau   = Vrr + Vii;
    const float delta = fminf(fmaxf(Vrr * Vii - Vri * Vri, EPSV), DELTA_MAX);
    const float s   = sqrtf(delta);
    const float t   = sqrtf(tau + 2.0f * s);
    const float rst = 1.0f / (s * t);
    const float Urr = (s + Vii) * rst;
    const float Uii = (s + Vrr) * rst;
    const float Uri = -Vri * rst;

    float wrr, wri, wii, br, bi;
    if (flags[1]) {
        wrr = ((const float*)Wrr_p)[j];  wri = ((const float*)Wri_p)[j];
        wii = ((const float*)Wii_p)[j];
        br  = ((const float*)Br_p)[j];   bi  = ((const float*)Bi_p)[j];
    } else {
        wrr = bf1(((const uint16_t*)Wrr_p)[j]);  wri = bf1(((const uint16_t*)Wri_p)[j]);
        wii = bf1(((const uint16_t*)Wii_p)[j]);
        br  = bf1(((const uint16_t*)Br_p)[j]);   bi  = bf1(((const uint16_t*)Bi_p)[j]);
    }
    const float Zrr = wrr * Urr + wri * Uri;
    const float Zri = wrr * Uri + wri * Uii;
    const float Zir = wri * Urr + wii * Uri;
    const float Zii = wri * Uri + wii * Uii;
    coef[0*NCOLS+j] = Zrr;
    coef[1*NCOLS+j] = Zri;
    coef[2*NCOLS+j] = Zir;
    coef[3*NCOLS+j] = Zii;
    coef[4*NCOLS+j] = br - Zrr * Mr - Zri * Mi;
    coef[5*NCOLS+j] = bi - Zir * Mr - Zii * Mi;
}

// ---------------- Pass 3: apply (column-stationary, coeffs in regs) ----------
// grid 2056 x block 256 => T = 526336 = 2048*257 (bijection tid->(r0,c)).
// Flat-contiguous: g = tid + k*526336 in u4 units — fill-identical stream.
// NT stores (equations across rounds 1-3: NT was ~17 us FASTER; also keeps
// x L3-resident for the next iteration's stats).
__global__ __launch_bounds__(256) void apply_kernel(
    const void* __restrict__ xr_p, const void* __restrict__ xi_p,
    const float* __restrict__ coef, const int* __restrict__ flags,
    void* __restrict__ out_p)
{
    const int tid = blockIdx.x * 256 + threadIdx.x;
    const int c  = tid % NG;
    const int r0 = tid / NG;            // [0,2048)
    const int col = c * 8;

    float Z[6][8];
    #pragma unroll
    for (int t = 0; t < 6; ++t) {
        const float4 lo = *(const float4*)(coef + t*NCOLS + col);
        const float4 hi = *(const float4*)(coef + t*NCOLS + col + 4);
        Z[t][0]=lo.x; Z[t][1]=lo.y; Z[t][2]=lo.z; Z[t][3]=lo.w;
        Z[t][4]=hi.x; Z[t][5]=hi.y; Z[t][6]=hi.z; Z[t][7]=hi.w;
    }

    if (flags[0]) {
        // -------- fp32 path --------
        const float4* xr4 = (const float4*)xr_p;
        const float4* xi4 = (const float4*)xi_p;
        f32x4* yr4 = (f32x4*)out_p;
        f32x4* yi4 = yr4 + (size_t)NROWS * NQ;     // yi after N*C*F floats
        #pragma unroll 2
        for (int k = 0; k < 8; ++k) {
            const size_t g = (size_t)(r0 + (k << 11)) * NQ + 2 * c;
            const float4 a0 = xr4[g], a1 = xr4[g + 1];
            const float4 b0 = xi4[g], b1 = xi4[g + 1];
            const float xrv[8] = {a0.x,a0.y,a0.z,a0.w,a1.x,a1.y,a1.z,a1.w};
            const float xiv[8] = {b0.x,b0.y,b0.z,b0.w,b1.x,b1.y,b1.z,b1.w};
            float yrv[8], yiv[8];
            #pragma unroll
            for (int j = 0; j < 8; ++j) {
                yrv[j] = Z[0][j]*xrv[j] + Z[1][j]*xiv[j] + Z[4][j];
                yiv[j] = Z[2][j]*xrv[j] + Z[3][j]*xiv[j] + Z[5][j];
            }
            const f32x4 s0 = {yrv[0], yrv[1], yrv[2], yrv[3]};
            const f32x4 s1 = {yrv[4], yrv[5], yrv[6], yrv[7]};
            const f32x4 t0 = {yiv[0], yiv[1], yiv[2], yiv[3]};
            const f32x4 t1 = {yiv[4], yiv[5], yiv[6], yiv[7]};
            __builtin_nontemporal_store(s0, yr4 + g);
            __builtin_nontemporal_store(s1, yr4 + g + 1);
            __builtin_nontemporal_store(t0, yi4 + g);
            __builtin_nontemporal_store(t1, yi4 + g + 1);
        }
    } else {
        // -------- bf16 path --------
        const uint4* xr4 = (const uint4*)xr_p;
        const uint4* xi4 = (const uint4*)xi_p;
        u32x4* yr4 = (u32x4*)out_p;
        u32x4* yi4 = yr4 + (size_t)NROWS * NG;     // yi after N*C*F bf16
        #pragma unroll 2
        for (int k = 0; k < 8; ++k) {
            const size_t g = (size_t)(r0 + (k << 11)) * NG + c;
            const uint4 a = xr4[g];
            const uint4 b = xi4[g];
            const uint32_t au[4] = {a.x, a.y, a.z, a.w};
            const uint32_t bu[4] = {b.x, b.y, b.z, b.w};
            uint32_t ou[4], pu[4];
            #pragma unroll
            for (int j = 0; j < 4; ++j) {
                const int e0 = 2*j, e1 = 2*j + 1;
                const float xr0 = bf_lo(au[j]), xr1 = bf_hi(au[j]);
                const float xi0 = bf_lo(bu[j]), xi1 = bf_hi(bu[j]);
                const float yr0 = Z[0][e0]*xr0 + Z[1][e0]*xi0 + Z[4][e0];
                const float yi0 = Z[2][e0]*xr0 + Z[3][e0]*xi0 + Z[5][e0];
                const float yr1 = Z[0][e1]*xr1 + Z[1][e1]*xi1 + Z[4][e1];
                const float yi1 = Z[2][e1]*xr1 + Z[3][e1]*xi1 + Z[5][e1];
                ou[j] = bf16pair(yr0, yr1);
                pu[j] = bf16pair(yi0, yi1);
            }
            const u32x4 o = {ou[0], ou[1], ou[2], ou[3]};
            const u32x4 p = {pu[0], pu[1], pu[2], pu[3]};
            __builtin_nontemporal_store(o, yr4 + g);
            __builtin_nontemporal_store(p, yi4 + g);
        }
    }
}

extern "C" void kernel_launch(void* const* d_in, const int* in_sizes, int n_in,
                              void* d_out, int out_size, void* d_ws, size_t ws_size,
                              hipStream_t stream)
{
    const void* xr_p = d_in[0];
    const void* xi_p = d_in[1];
    const void* Wrr  = d_in[2];
    const void* Wri  = d_in[3];
    const void* Wii  = d_in[4];
    const void* Br   = d_in[5];
    const void* Bi   = d_in[6];

    float* sums  = (float*)d_ws;                 // 5 * 2056 f32
    float* coef  = sums + NSUM;                  // 6 * 2056 f32
    int*   flags = (int*)(coef + 6 * NCOLS);     // 2 ints (pad to 4)
    float* partials = (float*)(flags + 4);       // NB * NSUM f32

    // NB must satisfy NB*1024 ≡ 0 mod lcm(257,514)=514 -> NB in {514, 257}
    const size_t base_bytes = (size_t)(NSUM + 6 * NCOLS + 4) * 4;
    int NB = 514;
    if (base_bytes + (size_t)NB * NSUM * 4 > ws_size) NB = 257;
    const int TT   = NB * 1024;
    const int nit8 = T8TOT / TT;     // 8 (NB=514) or 16 (NB=257), exact
    const int nit4 = T4TOT / TT;     // 16 or 32, exact

    detect_kernel<<<1, 512, 0, stream>>>((const uint32_t*)xr_p, (const uint32_t*)Wrr, flags);
    stats_kernel<<<NB, 1024, 0, stream>>>(xr_p, xi_p, flags, partials, TT, nit8, nit4);
    reduce_kernel<<<(NSUM + 63) / 64, 256, 0, stream>>>(partials, sums, NB);
    coef_kernel<<<(NCOLS + 255) / 256, 256, 0, stream>>>(sums, Wrr, Wri, Wii, Br, Bi, flags, coef);
    apply_kernel<<<2056, 256, 0, stream>>>(xr_p, xi_p, coef, flags, d_out);
}